// Round 6
// baseline (825.671 us; speedup 1.0000x reference)
//
#include <hip/hip_runtime.h>

// HierarchicalRouter: 32768 tokens x D=2048 fp32.
// Outputs (concat in d_out): final_weights [32768,2], dispatch_mask [32768,64], router_loss [1].
//
// Round-6: r0/r2/r5 all landed at 160-185us despite different structures because all of
// them drain vmcnt to 0 repeatedly (barriers or load-use chains) -> ~5KB/CU in flight
// -> ~1.5 TB/s effective (r2's L3-resident rocprof pass proved BW isn't the limit).
// Full rate needs ~22KB/CU continuously in flight (24.6 GB/s/CU x ~900ns).
// This version makes the main loop BARRIER-FREE by making weights immutable:
//  * prologue stages all 16 Wg rows into LDS once (128 KB, the known-good size),
//    one __syncthreads, then never again;
//  * the 4 We rows ride a register ping-pong, prefetched 1 chunk ahead (L1-resident);
//  * x rides a register ping-pong, prefetched 1 chunk ahead, nontemporal;
//  * per CU: 8 waves x ~4.5KB outstanding ≈ 36KB in flight, sustained.
// Geometry: 256 blocks x 512 threads (1 block/CU via 128.25KB LDS), wave owns 16
// contiguous tokens = 4 groups of TPW=4; acc[4][20]=80 regs, total ~175 < 256 cap
// from __launch_bounds__(512,2) -> no spill (r3/r4 lesson).
//
// Bit-exactness contract (r1 lesson: group logits are near-ties; accumulation order is
// part of the contract): per-lane slice layout (lane*4 within each 256-float chunk),
// chunk order 0..7, the dot4 expression, the 64-lane XOR butterfly and the epilogue are
// verbatim from the passing kernels. acc[t][r] chains are independent across r, so
// sourcing rows 0-15 from LDS and rows 16-19 from registers cannot change any bit.

#define NTOK    32768
#define DIM     2048
#define NG      16      // router groups (rows of Wg)
#define GS      4       // experts per group (rows of We)
#define NE      64      // total experts
#define NR      20      // NG + GS logit rows
#define DC      256     // D-chunk: 64 lanes x float4
#define NCHUNK  (DIM / DC)
#define TPB     512
#define TPW     4                   // tokens per group
#define NGRP    4                   // groups per wave
#define TOKW    (TPW * NGRP)        // tokens per wave = 16
#define TPBK    (TOKW * (TPB/64))   // tokens per block = 128
#define NSHADOW 32

typedef float f4 __attribute__((ext_vector_type(4)));

__device__ __forceinline__ f4 ldnt(const float* p) {
    return __builtin_nontemporal_load((const f4*)p);
}

__device__ __forceinline__ void gl_lds16(const float* g, float* l) {
    // async 16B/lane global->LDS; LDS dst = wave-uniform base + lane*16.
    __builtin_amdgcn_global_load_lds(
        (const __attribute__((address_space(1))) void*)g,
        (__attribute__((address_space(3))) void*)l,
        16, 0, 0);
}

// prefetch x chunk C of group G into DST[0..3] (per-lane 16B slices)
#define PF_X(DST, G, C) { _Pragma("unroll")                                   \
    for (int t_ = 0; t_ < TPW; ++t_)                                          \
        DST[t_] = ldnt(xw + (size_t)((G) * TPW + t_) * DIM + (C) * DC); }

// prefetch We chunk C into DST[0..3] (cached loads; We is L1/L2-resident)
#define PF_W(DST, C) { _Pragma("unroll")                                      \
    for (int r_ = 0; r_ < GS; ++r_)                                           \
        DST[r_] = *(const f4*)(wel + (size_t)r_ * DIM + (C) * DC); }

// accumulate chunk C: rows 0..15 from LDS, rows 16..19 from WV registers
#define COMP(C, XV, WV) {                                                     \
    _Pragma("unroll")                                                         \
    for (int r_ = 0; r_ < NG; ++r_) {                                         \
        f4 w_ = *(const f4*)(wlds + r_ * DIM + (C) * DC + lane4);             \
        _Pragma("unroll")                                                     \
        for (int t_ = 0; t_ < TPW; ++t_)                                      \
            acc[t_][r_] += XV[t_].x * w_.x + XV[t_].y * w_.y                  \
                         + XV[t_].z * w_.z + XV[t_].w * w_.w;                 \
    }                                                                         \
    _Pragma("unroll")                                                         \
    for (int r_ = 0; r_ < GS; ++r_) {                                         \
        f4 w_ = WV[r_];                                                       \
        _Pragma("unroll")                                                     \
        for (int t_ = 0; t_ < TPW; ++t_)                                      \
            acc[t_][NG + r_] += XV[t_].x * w_.x + XV[t_].y * w_.y             \
                              + XV[t_].z * w_.z + XV[t_].w * w_.w;            \
    } }

__global__ __launch_bounds__(TPB, 2) void router_main(
    const float* __restrict__ x,
    const float* __restrict__ Wg,
    const float* __restrict__ We,
    float* __restrict__ fw_out,
    float* __restrict__ dm_out,
    float* __restrict__ ws)
{
    __shared__ float wlds[NG * DIM];   // 128 KB: all 16 Wg rows, staged once
    __shared__ float lds_load[NE];     // per-block expert load
    __shared__ float lds_z;            // per-block z-loss partial

    const int tid   = threadIdx.x;
    const int lane  = tid & 63;
    const int wave  = tid >> 6;
    const int lane4 = lane * 4;

    if (tid < NE) lds_load[tid] = 0.0f;
    if (tid == 0) lds_z = 0.0f;

    const long twave = (long)blockIdx.x * TPBK + wave * TOKW;
    const float* xw  = x  + (size_t)twave * DIM + lane4;  // per-lane x base
    const float* wel = We + lane4;                        // per-lane We base

    // ---- prologue: stage 16 Wg rows (128 KB) once; 16 x 1KB segments per wave ----
    // flat float index: seg*256 in both Wg (row-major [16][2048]) and wlds.
    #pragma unroll
    for (int k = 0; k < 16; ++k) {
        const int seg = wave * 16 + k;               // wave-uniform
        gl_lds16(Wg + (size_t)seg * DC + lane4, wlds + seg * DC);
    }

    f4 xa[TPW], xb[TPW], wea[GS], web[GS];
    PF_X(xa, 0, 0);
    PF_W(wea, 0);
    __syncthreads();   // drains vmcnt: wlds complete (also covers lds_load init)

    // ---- barrier-free stream: 4 groups x 8 chunks, ping-pong 1 chunk ahead ----
    float acc[TPW][NR];
    #pragma unroll 1
    for (int g = 0; g < NGRP; ++g) {
        #pragma unroll
        for (int t = 0; t < TPW; ++t)
            #pragma unroll
            for (int r = 0; r < NR; ++r) acc[t][r] = 0.0f;

        PF_X(xb, g, 1);  PF_W(web, 1);  COMP(0, xa, wea);
        PF_X(xa, g, 2);  PF_W(wea, 2);  COMP(1, xb, web);
        PF_X(xb, g, 3);  PF_W(web, 3);  COMP(2, xa, wea);
        PF_X(xa, g, 4);  PF_W(wea, 4);  COMP(3, xb, web);
        PF_X(xb, g, 5);  PF_W(web, 5);  COMP(4, xa, wea);
        PF_X(xa, g, 6);  PF_W(wea, 6);  COMP(5, xb, web);
        PF_X(xb, g, 7);  PF_W(web, 7);  COMP(6, xa, wea);
        if (g + 1 < NGRP) { PF_X(xa, g + 1, 0); }     // next group's chunk 0
        PF_W(wea, 0);
        COMP(7, xb, web);

        // ---- full-wave butterfly reduce (identical to round-0) ----
        #pragma unroll
        for (int t = 0; t < TPW; ++t)
            #pragma unroll
            for (int r = 0; r < NR; ++r) {
                float v = acc[t][r];
                #pragma unroll
                for (int s = 32; s > 0; s >>= 1) v += __shfl_xor(v, s, 64);
                acc[t][r] = v;
            }

        // ---- epilogue (identical to round-0) ----
        #pragma unroll
        for (int t = 0; t < TPW; ++t) {
            float m16 = acc[t][0];
            #pragma unroll
            for (int r = 1; r < NG; ++r) m16 = fmaxf(m16, acc[t][r]);
            float den = 0.0f, bm = -1.0f; int gi = 0;
            #pragma unroll
            for (int r = 0; r < NG; ++r) {
                float e = expf(acc[t][r] - m16);
                den += e;
                if (e > bm) { bm = e; gi = r; }
            }
            float gw = bm / den;   // chosen_group_w (max softmax prob)

            float m4 = fmaxf(fmaxf(acc[t][NG + 0], acc[t][NG + 1]),
                             fmaxf(acc[t][NG + 2], acc[t][NG + 3]));
            float pr[GS]; float s4 = 0.0f;
            #pragma unroll
            for (int r = 0; r < GS; ++r) { pr[r] = expf(acc[t][NG + r] - m4); s4 += pr[r]; }
            float inv4 = 1.0f / s4;
            #pragma unroll
            for (int r = 0; r < GS; ++r) pr[r] *= inv4;

            int i0 = 0; float v0 = pr[0];
            #pragma unroll
            for (int r = 1; r < GS; ++r) if (pr[r] > v0) { v0 = pr[r]; i0 = r; }
            int i1 = -1; float v1 = -1.0f;
            #pragma unroll
            for (int r = 0; r < GS; ++r) if (r != i0 && pr[r] > v1) { v1 = pr[r]; i1 = r; }

            float nrm = v0 + v1 + 1e-7f;
            float sf0 = gw * (v0 / nrm);
            float sf1 = gw * (v1 / nrm);
            int   se0 = (gi << 2) + i0;
            int   se1 = (gi << 2) + i1;

            float sg = 0.0f;
            #pragma unroll
            for (int r = 0; r < NG; ++r) sg += acc[t][r] * acc[t][r];
            float sl = 0.0f;
            #pragma unroll
            for (int r = 0; r < GS; ++r) sl += acc[t][NG + r] * acc[t][NG + r];
            float sz = sg * (1.0f / 16.0f) + sl * 0.25f;

            const long tok = twave + g * TPW + t;
            if (lane < 16) {
                int col4 = lane * 4;
                float4 v;
                v.x = (col4 + 0 == se0) ? sf0 : (col4 + 0 == se1) ? sf1 : 0.0f;
                v.y = (col4 + 1 == se0) ? sf0 : (col4 + 1 == se1) ? sf1 : 0.0f;
                v.z = (col4 + 2 == se0) ? sf0 : (col4 + 2 == se1) ? sf1 : 0.0f;
                v.w = (col4 + 3 == se0) ? sf0 : (col4 + 3 == se1) ? sf1 : 0.0f;
                *(float4*)(dm_out + (size_t)tok * NE + col4) = v;
            } else if (lane == 16) {
                *(float2*)(fw_out + tok * 2) = make_float2(sf0, sf1);
            } else if (lane == 17) {
                atomicAdd(&lds_load[se0], sf0);
            } else if (lane == 18) {
                atomicAdd(&lds_load[se1], sf1);
            } else if (lane == 19) {
                atomicAdd(&lds_z, sz);
            }
        }
    }

    __syncthreads();
    if (tid < NE) atomicAdd(&ws[(blockIdx.x & (NSHADOW - 1)) * NE + tid], lds_load[tid]);
    if (tid == 0) atomicAdd(&ws[NSHADOW * NE], lds_z);
}

__global__ void router_finalize(const float* __restrict__ ws, float* __restrict__ out_loss)
{
    int e = threadIdx.x;  // 64 threads = 1 wave
    float load = 0.0f;
    #pragma unroll
    for (int s = 0; s < NSHADOW; ++s) load += ws[s * NE + e];
    float tot = load;
    #pragma unroll
    for (int s = 32; s > 0; s >>= 1) tot += __shfl_xor(tot, s, 64);
    float target = tot * (1.0f / NE);
    float dev = load - target;
    float sq = dev * dev;
    #pragma unroll
    for (int s = 32; s > 0; s >>= 1) sq += __shfl_xor(sq, s, 64);
    if (e == 0) {
        float lb = sq * (1.0f / NE);
        float z  = ws[NSHADOW * NE] * (1.0f / NTOK);
        out_loss[0] = 0.001f * (lb + z);
    }
}

extern "C" void kernel_launch(void* const* d_in, const int* in_sizes, int n_in,
                              void* d_out, int out_size, void* d_ws, size_t ws_size,
                              hipStream_t stream)
{
    const float* x  = (const float*)d_in[0];
    const float* Wg = (const float*)d_in[1];
    const float* We = (const float*)d_in[2];
    float* out = (float*)d_out;
    float* fw  = out;                                         // [32768, 2]
    float* dm  = out + (size_t)NTOK * 2;                      // [32768, 64]
    float* ls  = out + (size_t)NTOK * 2 + (size_t)NTOK * NE;  // [1]
    float* ws  = (float*)d_ws;

    hipMemsetAsync(ws, 0, (NSHADOW * NE + 1) * sizeof(float), stream);
    router_main<<<NTOK / TPBK, TPB, 0, stream>>>(x, Wg, We, fw, dm, ws);
    router_finalize<<<1, 64, 0, stream>>>(ws, ls);
}